// Round 2
// baseline (814.263 us; speedup 1.0000x reference)
//
#include <hip/hip_runtime.h>
#include <hip/hip_bf16.h>

typedef unsigned int u32;
typedef unsigned short u16;

#define DEVINL __device__ __forceinline__

constexpr int Nn  = 25000;
constexpr int Ee  = 100000;
constexpr int NCc = 8000;
constexpr int Aa  = 50000;
constexpr int ECc = 24000;
constexpr int TCOLS = 1088;   // 34 rows * 32 cols: k=0..31 -> T, k=32 -> x@b2, k=33 -> x@rootw+rootb

DEVINL float b2f(u16 u){ union{u32 i;float f;}v; v.i = ((u32)u)<<16; return v.f; }
DEVINL u16 f2b(float f){ union{float f;u32 i;}v; v.f=f; u32 i=v.i;
  return (u16)((i + 0x7fffu + ((i>>16)&1u)) >> 16); }

DEVINL float ldv(const float* p){ return *p; }
DEVINL float ldv(const u16* p){ return b2f(*p); }
DEVINL void stv(float* p, float v){ *p = v; }
DEVINL void stv(u16* p, float v){ *p = f2b(v); }

// ---------- dtype detection ----------
__global__ __launch_bounds__(256) void k_detect(const u16* __restrict__ p, int n,
                                                u32* __restrict__ maxbits, int* __restrict__ zcnt){
  int i0 = blockIdx.x*256 + threadIdx.x;
  float lm = 0.f; int lz = 0;
  for (int i = i0; i < n; i += gridDim.x*256){
    u16 v = p[i];
    if (v == 0) lz++;
    float f = fabsf(b2f(v));
    lm = fmaxf(lm, f);
  }
  #pragma unroll
  for (int off = 32; off; off >>= 1){
    lm = fmaxf(lm, __shfl_down(lm, off));
    lz += __shfl_down(lz, off);
  }
  if ((threadIdx.x & 63) == 0){
    atomicMax(maxbits, __float_as_uint(lm));
    atomicAdd(zcnt, lz);
  }
}

__global__ void k_setflag(const u32* maxbits, const int* zcnt, int n, int* flag){
  float m = __uint_as_float(*maxbits);
  *flag = (m > 1e6f || *zcnt > n/4) ? 1 : 0;   // 1 => inputs are f32
}

// convert input tensor (bf16 or f32 per flag) to f32
__global__ __launch_bounds__(256) void k_conv(const void* __restrict__ src, float* __restrict__ dst,
                                              int n, const int* __restrict__ flag){
  int i = blockIdx.x*256 + threadIdx.x;
  if (i >= n) return;
  if (*flag) dst[i] = ((const float*)src)[i];
  else       dst[i] = b2f(((const u16*)src)[i]);
}

__global__ __launch_bounds__(256) void k_store(const float* __restrict__ x, const float* __restrict__ c,
                                               void* __restrict__ out, const int* __restrict__ flag){
  int i = blockIdx.x*256 + threadIdx.x;
  int tot = Nn*32 + NCc*32;
  if (i >= tot) return;
  float v = (i < Nn*32) ? x[i] : c[i - Nn*32];
  if (*flag) ((float*)out)[i] = v;
  else       ((u16*)out)[i]   = f2b(v);
}

__global__ __launch_bounds__(256) void k_count(const int* __restrict__ idx, int n, int* __restrict__ deg){
  int i = blockIdx.x*256 + threadIdx.x;
  if (i < n) atomicAdd(&deg[idx[i]], 1);
}

// ---------- pipeline kernels (f32 math; T storage templated) ----------
template<typename TT>
__global__ __launch_bounds__(256) void k_feat_gemm(const float* __restrict__ x, int M,
                            const float* __restrict__ W2, const float* __restrict__ b2v,
                            const float* __restrict__ rw, const float* __restrict__ rb,
                            TT* __restrict__ T){
  __shared__ float xs[16][33];
  int tid = threadIdx.x;
  int n0 = blockIdx.x * 16;
  for (int idx = tid; idx < 16*32; idx += 256){
    int nl = idx >> 5, i = idx & 31;
    int n = n0 + nl;
    xs[nl][i] = (n < M) ? x[(size_t)n*32 + i] : 0.f;
  }
  __syncthreads();
  for (int idx = tid; idx < 16*TCOLS; idx += 256){
    int nl = idx / TCOLS, col = idx - nl*TCOLS;
    int n = n0 + nl;
    if (n >= M) continue;
    float acc = 0.f;
    if (col < 1024){
      const float* w = W2 + ((col >> 5) << 10) + (col & 31);   // w2[k][i*32+o]
      #pragma unroll
      for (int i = 0; i < 32; i++) acc += xs[nl][i]*w[i*32];
    } else if (col < 1056){
      int o = col - 1024;
      #pragma unroll
      for (int i = 0; i < 32; i++) acc += xs[nl][i]*b2v[i*32+o];
    } else {
      int o = col - 1056;
      #pragma unroll
      for (int i = 0; i < 32; i++) acc += xs[nl][i]*rw[i*32+o];
      acc += rb[o];
    }
    stv(&T[(size_t)n*TCOLS + col], acc);
  }
}

__global__ __launch_bounds__(256) void k_edge_h(const float* __restrict__ ef, int E_,
                         const float* __restrict__ w1, const float* __restrict__ b1,
                         float* __restrict__ h){
  __shared__ float wsm[256], bs[32];
  int tid = threadIdx.x;
  wsm[tid] = w1[tid];
  if (tid < 32) bs[tid] = b1[tid];
  __syncthreads();
  int e = blockIdx.x*256 + tid;
  if (e >= E_) return;
  const float4* e4 = (const float4*)(ef + (size_t)e*8);
  float4 q0 = e4[0], q1 = e4[1];
  float ev[8] = { q0.x,q0.y,q0.z,q0.w, q1.x,q1.y,q1.z,q1.w };
  float* hp = h + (size_t)e*32;
  #pragma unroll
  for (int o = 0; o < 32; o++){
    float a = bs[o];
    #pragma unroll
    for (int j = 0; j < 8; j++) a += ev[j]*wsm[j*32+o];
    hp[o] = fmaxf(a, 0.f);
  }
}

// msg[e][o] = sum_{k<33} h'[e][k]*T[src[e]][k][o]   (h'[32]=1 picks up b2 row)
template<typename TT>
__global__ __launch_bounds__(256) void k_edge_msg(const int* __restrict__ src, const int* __restrict__ dst, int E_,
                           const float* __restrict__ h, const TT* __restrict__ T,
                           float* __restrict__ agg){
  __shared__ float hs[16][34];
  int tid = threadIdx.x;
  int e0 = blockIdx.x * 16;
  {
    int el = tid >> 4, kk = tid & 15;
    float2 v = make_float2(0.f, 0.f);
    if (e0 + el < E_) v = ((const float2*)h)[(size_t)(e0+el)*16 + kk];
    hs[el][2*kk]   = v.x;
    hs[el][2*kk+1] = v.y;
    if (kk == 0) hs[el][32] = 1.0f;
  }
  __syncthreads();
  int el = tid >> 4, op = tid & 15;
  int e = e0 + el;
  if (e >= E_) return;
  int sn = src[e], dn = dst[e];
  const TT* Tp = T + (size_t)sn*TCOLS + 2*op;
  float a0 = 0.f, a1 = 0.f;
  #pragma unroll
  for (int k = 0; k < 33; k++){
    float hk = hs[el][k];
    a0 += hk * ldv(Tp + k*32);
    a1 += hk * ldv(Tp + k*32 + 1);
  }
  float* ap = agg + (size_t)dn*32 + 2*op;
  atomicAdd(ap,   a0);
  atomicAdd(ap+1, a1);
}

template<typename TT>
__global__ __launch_bounds__(256) void k_update_relu(const float* __restrict__ agg, const int* __restrict__ deg,
                              const TT* __restrict__ T, int M, float* __restrict__ out){
  int i = blockIdx.x*256 + threadIdx.x;
  if (i >= M*32) return;
  int n = i >> 5, o = i & 31;
  int dg = deg[n];
  float d = (float)(dg > 1 ? dg : 1);
  float v = agg[i]/d + ldv(&T[(size_t)n*TCOLS + 1056 + o]);
  out[i] = fmaxf(v, 0.f);
}

__global__ __launch_bounds__(256) void k_lin32(const float* __restrict__ x, int M,
                        const float* __restrict__ w, const float* __restrict__ b,
                        float* __restrict__ out){
  __shared__ float wsm[1024], bs[32];
  int tid = threadIdx.x;
  for (int idx = tid; idx < 1024; idx += 256) wsm[idx] = w[idx];
  if (tid < 32) bs[tid] = b[tid];
  __syncthreads();
  int i = blockIdx.x*256 + tid;
  if (i >= M*32) return;
  int n = i >> 5, o = i & 31;
  const float* xr = x + (size_t)n*32;
  float acc = bs[o];
  #pragma unroll
  for (int j = 0; j < 32; j++) acc += xr[j]*wsm[j*32+o];
  out[i] = acc;
}

__global__ __launch_bounds__(256) void k_scatter(const int* __restrict__ gidx, const int* __restrict__ sidx, int A_,
                          const float* __restrict__ m, float* __restrict__ agg){
  int i = blockIdx.x*256 + threadIdx.x;
  if (i >= A_*32) return;
  int a = i >> 5, o = i & 31;
  atomicAdd(&agg[(size_t)sidx[a]*32 + o], m[(size_t)gidx[a]*32 + o]);
}

__global__ __launch_bounds__(256) void k_add_mean(const float* __restrict__ base, const float* __restrict__ agg,
                           const int* __restrict__ deg, int M, float* __restrict__ out){
  int i = blockIdx.x*256 + threadIdx.x;
  if (i >= M*32) return;
  int n = i >> 5;
  int dg = deg[n];
  float d = (float)(dg > 1 ? dg : 1);
  out[i] = base[i] + agg[i]/d;
}

// ---------- host pipeline ----------
template<typename TT>
static void run_pipeline(float* xA, float* xB, float* cA, float* cB, float* m,
                         float* agg, float* cagg,
                         const int* deg_nd, const int* deg_ce, const int* deg_n2c, const int* deg_c2n,
                         const int* ei, const int* cei, const int* n2c,
                         const float* ef32, const float* cef32,
                         const float* nn1w, const float* nn1b, const float* nn2w, const float* nn2b,
                         const float* rootw, const float* rootb, const float* n2cw, const float* n2cb,
                         const float* cnn1w, const float* cnn1b, const float* cnn2w, const float* cnn2b,
                         const float* crootw, const float* crootb, const float* c2nw, const float* c2nb,
                         float* hb, TT* Tb, hipStream_t stream)
{
  auto nb = [](int n){ return (n + 255)/256; };
  for (int l = 0; l < 2; l++){
    // node NNConv
    k_feat_gemm<TT><<<(Nn+15)/16,256,0,stream>>>(xA, Nn, nn2w + (size_t)l*32768, nn2b + l*1024,
                                                 rootw + l*1024, rootb + l*32, Tb);
    k_edge_h<<<nb(Ee),256,0,stream>>>(ef32, Ee, nn1w + l*256, nn1b + l*32, hb);
    hipMemsetAsync(agg, 0, (size_t)Nn*32*4, stream);
    k_edge_msg<TT><<<(Ee+15)/16,256,0,stream>>>(ei, ei+Ee, Ee, hb, Tb, agg);
    k_update_relu<TT><<<nb(Nn*32),256,0,stream>>>(agg, deg_nd, Tb, Nn, xB);
    // Node2Clique
    k_lin32<<<nb(Nn*32),256,0,stream>>>(xB, Nn, n2cw + l*1024, n2cb + l*32, m);
    hipMemsetAsync(cagg, 0, (size_t)NCc*32*4, stream);
    k_scatter<<<nb(Aa*32),256,0,stream>>>(n2c, n2c+Aa, Aa, m, cagg);
    k_add_mean<<<nb(NCc*32),256,0,stream>>>(cA, cagg, deg_n2c, NCc, cB);
    // clique NNConv
    k_feat_gemm<TT><<<(NCc+15)/16,256,0,stream>>>(cB, NCc, cnn2w + (size_t)l*32768, cnn2b + l*1024,
                                                  crootw + l*1024, crootb + l*32, Tb);
    k_edge_h<<<nb(ECc),256,0,stream>>>(cef32, ECc, cnn1w + l*256, cnn1b + l*32, hb);
    hipMemsetAsync(cagg, 0, (size_t)NCc*32*4, stream);
    k_edge_msg<TT><<<(ECc+15)/16,256,0,stream>>>(cei, cei+ECc, ECc, hb, Tb, cagg);
    k_update_relu<TT><<<nb(NCc*32),256,0,stream>>>(cagg, deg_ce, Tb, NCc, cA);
    // Clique2Node
    k_lin32<<<nb(NCc*32),256,0,stream>>>(cA, NCc, c2nw + l*1024, c2nb + l*32, m);
    hipMemsetAsync(agg, 0, (size_t)Nn*32*4, stream);
    k_scatter<<<nb(Aa*32),256,0,stream>>>(n2c+Aa, n2c, Aa, m, agg);
    k_add_mean<<<nb(Nn*32),256,0,stream>>>(xB, agg, deg_c2n, Nn, xA);
  }
}

extern "C" void kernel_launch(void* const* d_in, const int* in_sizes, int n_in,
                              void* d_out, int out_size, void* d_ws, size_t ws_size,
                              hipStream_t stream){
  const int* ei  = (const int*)d_in[1];
  const int* n2c = (const int*)d_in[4];
  const int* cei = (const int*)d_in[5];

  char* ws = (char*)d_ws;
  size_t off = 0;
  auto alloc = [&](size_t bytes){ void* p = ws + off; off += (bytes + 255) & ~(size_t)255; return p; };

  // detection scratch
  u32* maxbits = (u32*)alloc(256);
  int* zcnt = (int*)((char*)maxbits + 4);
  int* flag = (int*)((char*)maxbits + 8);

  float* xA   = (float*)alloc((size_t)Nn*32*4);
  float* xB   = (float*)alloc((size_t)Nn*32*4);
  float* cA   = (float*)alloc((size_t)NCc*32*4);
  float* cB   = (float*)alloc((size_t)NCc*32*4);
  float* m    = (float*)alloc((size_t)Nn*32*4);
  float* agg  = (float*)alloc((size_t)Nn*32*4);
  float* cagg = (float*)alloc((size_t)NCc*32*4);
  int* deg_nd  = (int*)alloc((size_t)Nn*4);
  int* deg_ce  = (int*)alloc((size_t)NCc*4);
  int* deg_n2c = (int*)alloc((size_t)NCc*4);
  int* deg_c2n = (int*)alloc((size_t)Nn*4);
  float* ef32  = (float*)alloc((size_t)Ee*8*4);
  float* cef32 = (float*)alloc((size_t)ECc*8*4);

  const int widx[16] = {7,8,9,10,11,12,13,14,15,16,17,18,19,20,21,22};
  float* wf[16];
  for (int j = 0; j < 16; j++) wf[j] = (float*)alloc((size_t)in_sizes[widx[j]]*4);

  float* hb = (float*)alloc((size_t)Ee*32*4);

  // T storage: f32 if it fits in remaining workspace, else bf16
  size_t t32_bytes = (size_t)Nn*TCOLS*4;
  bool t32 = (off + t32_bytes + 256) <= ws_size;
  void* Tb = alloc(t32 ? t32_bytes : (size_t)Nn*TCOLS*2);

  auto nb = [](int n){ return (n + 255)/256; };

  // 1. dtype detection on node_features
  hipMemsetAsync(maxbits, 0, 256, stream);
  k_detect<<<256,256,0,stream>>>((const u16*)d_in[0], Nn*32, maxbits, zcnt);
  k_setflag<<<1,1,0,stream>>>(maxbits, zcnt, Nn*32, flag);

  // 2. convert all float tensors to f32
  k_conv<<<nb(Nn*32),256,0,stream>>>(d_in[0], xA, Nn*32, flag);
  k_conv<<<nb(NCc*32),256,0,stream>>>(d_in[3], cA, NCc*32, flag);
  k_conv<<<nb(Ee*8),256,0,stream>>>(d_in[2], ef32, Ee*8, flag);
  k_conv<<<nb(ECc*8),256,0,stream>>>(d_in[6], cef32, ECc*8, flag);
  for (int j = 0; j < 16; j++)
    k_conv<<<nb(in_sizes[widx[j]]),256,0,stream>>>(d_in[widx[j]], wf[j], in_sizes[widx[j]], flag);

  // 3. degrees
  hipMemsetAsync(deg_nd, 0, (size_t)Nn*4, stream);
  hipMemsetAsync(deg_ce, 0, (size_t)NCc*4, stream);
  hipMemsetAsync(deg_n2c, 0, (size_t)NCc*4, stream);
  hipMemsetAsync(deg_c2n, 0, (size_t)Nn*4, stream);
  k_count<<<nb(Ee),256,0,stream>>>(ei + Ee, Ee, deg_nd);
  k_count<<<nb(ECc),256,0,stream>>>(cei + ECc, ECc, deg_ce);
  k_count<<<nb(Aa),256,0,stream>>>(n2c + Aa, Aa, deg_n2c);
  k_count<<<nb(Aa),256,0,stream>>>(n2c, Aa, deg_c2n);

  // 4. the 2-layer pipeline
  if (t32)
    run_pipeline<float>(xA, xB, cA, cB, m, agg, cagg, deg_nd, deg_ce, deg_n2c, deg_c2n,
                        ei, cei, n2c, ef32, cef32,
                        wf[0], wf[1], wf[2], wf[3], wf[4], wf[5], wf[6], wf[7],
                        wf[8], wf[9], wf[10], wf[11], wf[12], wf[13], wf[14], wf[15],
                        hb, (float*)Tb, stream);
  else
    run_pipeline<u16>(xA, xB, cA, cB, m, agg, cagg, deg_nd, deg_ce, deg_n2c, deg_c2n,
                      ei, cei, n2c, ef32, cef32,
                      wf[0], wf[1], wf[2], wf[3], wf[4], wf[5], wf[6], wf[7],
                      wf[8], wf[9], wf[10], wf[11], wf[12], wf[13], wf[14], wf[15],
                      hb, (u16*)Tb, stream);

  // 5. store output (dtype per flag)
  k_store<<<nb(Nn*32 + NCc*32),256,0,stream>>>(xA, cA, d_out, flag);
}

// Round 3
// 607.991 us; speedup vs baseline: 1.3393x; 1.3393x over previous
//
#include <hip/hip_runtime.h>
#include <hip/hip_bf16.h>

typedef unsigned int u32;
typedef unsigned short u16;

#define DEVINL __device__ __forceinline__

constexpr int Nn  = 25000;
constexpr int Ee  = 100000;
constexpr int NCc = 8000;
constexpr int Aa  = 50000;
constexpr int ECc = 24000;
constexpr int TCOLS = 1088;   // 34 rows * 32 cols: k=0..31 -> T, k=32 -> x@b2, k=33 -> x@rootw+rootb

typedef float f32x4 __attribute__((ext_vector_type(4)));
typedef short s16x8 __attribute__((ext_vector_type(8)));

DEVINL float b2f(u16 u){ union{u32 i;float f;}v; v.i = ((u32)u)<<16; return v.f; }
DEVINL float bfl(u32 u){ union{u32 i;float f;}v; v.i = u<<16; return v.f; }
DEVINL float bfh(u32 u){ union{u32 i;float f;}v; v.i = u & 0xffff0000u; return v.f; }
DEVINL u16 f2b(float f){ union{float f;u32 i;}v; v.f=f; u32 i=v.i;
  return (u16)((i + 0x7fffu + ((i>>16)&1u)) >> 16); }

// ---------- dtype detection ----------
__global__ __launch_bounds__(256) void k_detect(const u16* __restrict__ p, int n,
                                                u32* __restrict__ maxbits, int* __restrict__ zcnt){
  int i0 = blockIdx.x*256 + threadIdx.x;
  float lm = 0.f; int lz = 0;
  for (int i = i0; i < n; i += gridDim.x*256){
    u16 v = p[i];
    if (v == 0) lz++;
    float f = fabsf(b2f(v));
    lm = fmaxf(lm, f);
  }
  #pragma unroll
  for (int off = 32; off; off >>= 1){
    lm = fmaxf(lm, __shfl_down(lm, off));
    lz += __shfl_down(lz, off);
  }
  if ((threadIdx.x & 63) == 0){
    atomicMax(maxbits, __float_as_uint(lm));
    atomicAdd(zcnt, lz);
  }
}

__global__ void k_setflag(const u32* maxbits, const int* zcnt, int n, int* flag){
  float m = __uint_as_float(*maxbits);
  *flag = (m > 1e6f || *zcnt > n/4) ? 1 : 0;   // 1 => inputs are f32
}

__global__ __launch_bounds__(256) void k_conv(const void* __restrict__ src, float* __restrict__ dst,
                                              int n, const int* __restrict__ flag){
  int i = blockIdx.x*256 + threadIdx.x;
  if (i >= n) return;
  if (*flag) dst[i] = ((const float*)src)[i];
  else       dst[i] = b2f(((const u16*)src)[i]);
}

__global__ __launch_bounds__(256) void k_store(const float* __restrict__ x, const float* __restrict__ c,
                                               void* __restrict__ out, const int* __restrict__ flag){
  int i = blockIdx.x*256 + threadIdx.x;
  int tot = Nn*32 + NCc*32;
  if (i >= tot) return;
  float v = (i < Nn*32) ? x[i] : c[i - Nn*32];
  if (*flag) ((float*)out)[i] = v;
  else       ((u16*)out)[i]   = f2b(v);
}

__global__ __launch_bounds__(256) void k_count(const int* __restrict__ idx, int n, int* __restrict__ deg){
  int i = blockIdx.x*256 + threadIdx.x;
  if (i < n) atomicAdd(&deg[idx[i]], 1);
}

// ---------- weight pack: Wp[col][i] bf16, col in [0,1088), i in [0,32) ----------
__global__ __launch_bounds__(256) void k_wpack(const float* __restrict__ W2, const float* __restrict__ b2v,
                                               const float* __restrict__ rw, u16* __restrict__ Wp){
  int i = blockIdx.x*256 + threadIdx.x;   // i = col*32 + ii
  if (i >= TCOLS*32) return;
  int col = i >> 5, ii = i & 31;
  float v;
  if (col < 1024)      v = W2[((col>>5)<<10) + (ii<<5) + (col&31)];
  else if (col < 1056) v = b2v[(ii<<5) + (col-1024)];
  else                 v = rw[(ii<<5) + (col-1056)];
  Wp[i] = f2b(v);
}

// ---------- MFMA feat gemm: T[M x 1088] = X[M x 32] * B[32 x 1088], T bf16 ----------
// one wave: 16 nodes (A-frag loaded once), loops 68 col-tiles of 16
__global__ __launch_bounds__(256) void k_feat_gemm_mfma(const float* __restrict__ x, int M,
                            const u16* __restrict__ Wp, const float* __restrict__ rb,
                            u16* __restrict__ T){
  int wave = threadIdx.x >> 6;
  int lane = threadIdx.x & 63;
  int quad = lane >> 4, lm = lane & 15;
  int ntile = blockIdx.x*64 + wave*16;
  int n = ntile + lm;
  int nc = n < M ? n : M-1;
  const float* xp = x + (size_t)nc*32 + quad*8;
  s16x8 afrag;
  #pragma unroll
  for (int j = 0; j < 8; j++) afrag[j] = (short)f2b(xp[j]);
  int rowbase = ntile + quad*4;
  for (int ct = 0; ct < 68; ct++){
    int col = ct*16 + lm;
    s16x8 bfrag = *(const s16x8*)(Wp + (size_t)col*32 + quad*8);
    f32x4 acc = {0.f, 0.f, 0.f, 0.f};
    acc = __builtin_amdgcn_mfma_f32_16x16x32_bf16(afrag, bfrag, acc, 0, 0, 0);
    float radd = (ct >= 66) ? rb[col - 1056] : 0.f;
    #pragma unroll
    for (int r = 0; r < 4; r++){
      int row = rowbase + r;
      if (row < M) T[(size_t)row*TCOLS + col] = f2b(acc[r] + radd);
    }
  }
}

// ---------- edge MLP ----------
__global__ __launch_bounds__(256) void k_edge_h(const float* __restrict__ ef, int E_,
                         const float* __restrict__ w1, const float* __restrict__ b1,
                         float* __restrict__ h){
  __shared__ float wsm[256], bs[32];
  int tid = threadIdx.x;
  wsm[tid] = w1[tid];
  if (tid < 32) bs[tid] = b1[tid];
  __syncthreads();
  int e = blockIdx.x*256 + tid;
  if (e >= E_) return;
  const float4* e4 = (const float4*)(ef + (size_t)e*8);
  float4 q0 = e4[0], q1 = e4[1];
  float ev[8] = { q0.x,q0.y,q0.z,q0.w, q1.x,q1.y,q1.z,q1.w };
  float* hp = h + (size_t)e*32;
  #pragma unroll
  for (int o = 0; o < 32; o++){
    float a = bs[o];
    #pragma unroll
    for (int j = 0; j < 8; j++) a += ev[j]*wsm[j*32+o];
    hp[o] = fmaxf(a, 0.f);
  }
}

// msg[e][o] = sum_{k<33} h'[e][k]*T[src[e]][k][o]   (h'[32]=1 picks up b2 row), T bf16
__global__ __launch_bounds__(256) void k_edge_msg(const int* __restrict__ src, const int* __restrict__ dst, int E_,
                           const float* __restrict__ h, const u16* __restrict__ T,
                           float* __restrict__ agg){
  __shared__ float hs[16][34];
  int tid = threadIdx.x;
  int e0 = blockIdx.x * 16;
  {
    int el = tid >> 4, kk = tid & 15;
    float2 v = make_float2(0.f, 0.f);
    if (e0 + el < E_) v = ((const float2*)h)[(size_t)(e0+el)*16 + kk];
    hs[el][2*kk]   = v.x;
    hs[el][2*kk+1] = v.y;
    if (kk == 0) hs[el][32] = 1.0f;
  }
  __syncthreads();
  int el = tid >> 4, op = tid & 15;
  int e = e0 + el;
  if (e >= E_) return;
  int sn = src[e], dn = dst[e];
  const u32* Tp = (const u32*)T + (size_t)sn*(TCOLS/2) + op;
  float a0 = 0.f, a1 = 0.f;
  #pragma unroll
  for (int k = 0; k < 33; k++){
    u32 v = Tp[(size_t)k*16];
    float hk = hs[el][k];
    a0 += hk * bfl(v);
    a1 += hk * bfh(v);
  }
  float* ap = agg + (size_t)dn*32 + 2*op;
  atomicAdd(ap,   a0);
  atomicAdd(ap+1, a1);
}

__global__ __launch_bounds__(256) void k_update_relu(const float* __restrict__ agg, const int* __restrict__ deg,
                              const u16* __restrict__ T, int M, float* __restrict__ out){
  int i = blockIdx.x*256 + threadIdx.x;
  if (i >= M*32) return;
  int n = i >> 5, o = i & 31;
  int dg = deg[n];
  float d = (float)(dg > 1 ? dg : 1);
  float v = agg[i]/d + b2f(T[(size_t)n*TCOLS + 1056 + o]);
  out[i] = fmaxf(v, 0.f);
}

__global__ __launch_bounds__(256) void k_lin32(const float* __restrict__ x, int M,
                        const float* __restrict__ w, const float* __restrict__ b,
                        float* __restrict__ out){
  __shared__ float wsm[1024], bs[32];
  int tid = threadIdx.x;
  for (int idx = tid; idx < 1024; idx += 256) wsm[idx] = w[idx];
  if (tid < 32) bs[tid] = b[tid];
  __syncthreads();
  int i = blockIdx.x*256 + tid;
  if (i >= M*32) return;
  int n = i >> 5, o = i & 31;
  const float* xr = x + (size_t)n*32;
  float acc = bs[o];
  #pragma unroll
  for (int j = 0; j < 32; j++) acc += xr[j]*wsm[j*32+o];
  out[i] = acc;
}

__global__ __launch_bounds__(256) void k_scatter(const int* __restrict__ gidx, const int* __restrict__ sidx, int A_,
                          const float* __restrict__ m, float* __restrict__ agg){
  int i = blockIdx.x*256 + threadIdx.x;
  if (i >= A_*32) return;
  int a = i >> 5, o = i & 31;
  atomicAdd(&agg[(size_t)sidx[a]*32 + o], m[(size_t)gidx[a]*32 + o]);
}

__global__ __launch_bounds__(256) void k_add_mean(const float* __restrict__ base, const float* __restrict__ agg,
                           const int* __restrict__ deg, int M, float* __restrict__ out){
  int i = blockIdx.x*256 + threadIdx.x;
  if (i >= M*32) return;
  int n = i >> 5;
  int dg = deg[n];
  float d = (float)(dg > 1 ? dg : 1);
  out[i] = base[i] + agg[i]/d;
}

extern "C" void kernel_launch(void* const* d_in, const int* in_sizes, int n_in,
                              void* d_out, int out_size, void* d_ws, size_t ws_size,
                              hipStream_t stream){
  const int* ei  = (const int*)d_in[1];
  const int* n2c = (const int*)d_in[4];
  const int* cei = (const int*)d_in[5];

  char* ws = (char*)d_ws;
  size_t off = 0;
  auto alloc = [&](size_t bytes){ void* p = ws + off; off += (bytes + 255) & ~(size_t)255; return p; };

  u32* maxbits = (u32*)alloc(256);
  int* zcnt = (int*)((char*)maxbits + 4);
  int* flag = (int*)((char*)maxbits + 8);

  float* xA   = (float*)alloc((size_t)Nn*32*4);
  float* xB   = (float*)alloc((size_t)Nn*32*4);
  float* cA   = (float*)alloc((size_t)NCc*32*4);
  float* cB   = (float*)alloc((size_t)NCc*32*4);
  float* m    = (float*)alloc((size_t)Nn*32*4);
  float* agg  = (float*)alloc((size_t)Nn*32*4);
  float* cagg = (float*)alloc((size_t)NCc*32*4);
  int* deg_nd  = (int*)alloc((size_t)Nn*4);
  int* deg_ce  = (int*)alloc((size_t)NCc*4);
  int* deg_n2c = (int*)alloc((size_t)NCc*4);
  int* deg_c2n = (int*)alloc((size_t)Nn*4);
  float* ef32  = (float*)alloc((size_t)Ee*8*4);
  float* cef32 = (float*)alloc((size_t)ECc*8*4);

  const int widx[16] = {7,8,9,10,11,12,13,14,15,16,17,18,19,20,21,22};
  float* wf[16];
  for (int j = 0; j < 16; j++) wf[j] = (float*)alloc((size_t)in_sizes[widx[j]]*4);

  float* hb = (float*)alloc((size_t)Ee*32*4);
  u16* Wp  = (u16*)alloc((size_t)TCOLS*32*2);
  u16* Tb  = (u16*)alloc((size_t)Nn*TCOLS*2);

  auto nb = [](int n){ return (n + 255)/256; };

  // 1. dtype detection on node_features
  hipMemsetAsync(maxbits, 0, 256, stream);
  k_detect<<<256,256,0,stream>>>((const u16*)d_in[0], Nn*32, maxbits, zcnt);
  k_setflag<<<1,1,0,stream>>>(maxbits, zcnt, Nn*32, flag);

  // 2. convert all float tensors to f32
  k_conv<<<nb(Nn*32),256,0,stream>>>(d_in[0], xA, Nn*32, flag);
  k_conv<<<nb(NCc*32),256,0,stream>>>(d_in[3], cA, NCc*32, flag);
  k_conv<<<nb(Ee*8),256,0,stream>>>(d_in[2], ef32, Ee*8, flag);
  k_conv<<<nb(ECc*8),256,0,stream>>>(d_in[6], cef32, ECc*8, flag);
  for (int j = 0; j < 16; j++)
    k_conv<<<nb(in_sizes[widx[j]]),256,0,stream>>>(d_in[widx[j]], wf[j], in_sizes[widx[j]], flag);

  // weight aliases (f32 copies)
  const float *nn1w=wf[0], *nn1b=wf[1], *nn2w=wf[2], *nn2b=wf[3], *rootw=wf[4], *rootb=wf[5],
              *n2cw=wf[6], *n2cb=wf[7], *cnn1w=wf[8], *cnn1b=wf[9], *cnn2w=wf[10], *cnn2b=wf[11],
              *crootw=wf[12], *crootb=wf[13], *c2nw=wf[14], *c2nb=wf[15];

  // 3. degrees
  hipMemsetAsync(deg_nd, 0, (size_t)Nn*4, stream);
  hipMemsetAsync(deg_ce, 0, (size_t)NCc*4, stream);
  hipMemsetAsync(deg_n2c, 0, (size_t)NCc*4, stream);
  hipMemsetAsync(deg_c2n, 0, (size_t)Nn*4, stream);
  k_count<<<nb(Ee),256,0,stream>>>(ei + Ee, Ee, deg_nd);
  k_count<<<nb(ECc),256,0,stream>>>(cei + ECc, ECc, deg_ce);
  k_count<<<nb(Aa),256,0,stream>>>(n2c + Aa, Aa, deg_n2c);
  k_count<<<nb(Aa),256,0,stream>>>(n2c, Aa, deg_c2n);

  // 4. pipeline
  for (int l = 0; l < 2; l++){
    // ---- node NNConv ----
    k_wpack<<<nb(TCOLS*32),256,0,stream>>>(nn2w + (size_t)l*32768, nn2b + l*1024, rootw + l*1024, Wp);
    k_feat_gemm_mfma<<<(Nn+63)/64,256,0,stream>>>(xA, Nn, Wp, rootb + l*32, Tb);
    k_edge_h<<<nb(Ee),256,0,stream>>>(ef32, Ee, nn1w + l*256, nn1b + l*32, hb);
    hipMemsetAsync(agg, 0, (size_t)Nn*32*4, stream);
    k_edge_msg<<<(Ee+15)/16,256,0,stream>>>(ei, ei+Ee, Ee, hb, Tb, agg);
    k_update_relu<<<nb(Nn*32),256,0,stream>>>(agg, deg_nd, Tb, Nn, xB);
    // ---- Node2Clique ----
    k_lin32<<<nb(Nn*32),256,0,stream>>>(xB, Nn, n2cw + l*1024, n2cb + l*32, m);
    hipMemsetAsync(cagg, 0, (size_t)NCc*32*4, stream);
    k_scatter<<<nb(Aa*32),256,0,stream>>>(n2c, n2c+Aa, Aa, m, cagg);
    k_add_mean<<<nb(NCc*32),256,0,stream>>>(cA, cagg, deg_n2c, NCc, cB);
    // ---- clique NNConv ----
    k_wpack<<<nb(TCOLS*32),256,0,stream>>>(cnn2w + (size_t)l*32768, cnn2b + l*1024, crootw + l*1024, Wp);
    k_feat_gemm_mfma<<<(NCc+63)/64,256,0,stream>>>(cB, NCc, Wp, crootb + l*32, Tb);
    k_edge_h<<<nb(ECc),256,0,stream>>>(cef32, ECc, cnn1w + l*256, cnn1b + l*32, hb);
    hipMemsetAsync(cagg, 0, (size_t)NCc*32*4, stream);
    k_edge_msg<<<(ECc+15)/16,256,0,stream>>>(cei, cei+ECc, ECc, hb, Tb, cagg);
    k_update_relu<<<nb(NCc*32),256,0,stream>>>(cagg, deg_ce, Tb, NCc, cA);
    // ---- Clique2Node ----
    k_lin32<<<nb(NCc*32),256,0,stream>>>(cA, NCc, c2nw + l*1024, c2nb + l*32, m);
    hipMemsetAsync(agg, 0, (size_t)Nn*32*4, stream);
    k_scatter<<<nb(Aa*32),256,0,stream>>>(n2c+Aa, n2c, Aa, m, agg);
    k_add_mean<<<nb(Nn*32),256,0,stream>>>(xB, agg, deg_c2n, Nn, xA);
  }
  k_store<<<nb(Nn*32 + NCc*32),256,0,stream>>>(xA, cA, d_out, flag);
}

// Round 4
// 458.240 us; speedup vs baseline: 1.7769x; 1.3268x over previous
//
#include <hip/hip_runtime.h>
#include <hip/hip_bf16.h>

typedef unsigned int u32;
typedef unsigned short u16;

#define DEVINL __device__ __forceinline__

constexpr int Nn  = 25000;
constexpr int Ee  = 100000;
constexpr int NCc = 8000;
constexpr int Aa  = 50000;
constexpr int ECc = 24000;
constexpr int TCOLS = 1088;   // 34 rows * 32 cols: k=0..31 -> T, k=32 -> x@b2, k=33 -> x@rootw+rootb

typedef float f32x4 __attribute__((ext_vector_type(4)));
typedef short s16x8 __attribute__((ext_vector_type(8)));

DEVINL float b2f(u16 u){ union{u32 i;float f;}v; v.i = ((u32)u)<<16; return v.f; }
DEVINL float bfl(u32 u){ union{u32 i;float f;}v; v.i = u<<16; return v.f; }
DEVINL float bfh(u32 u){ union{u32 i;float f;}v; v.i = u & 0xffff0000u; return v.f; }
DEVINL u16 f2b(float f){ union{float f;u32 i;}v; v.f=f; u32 i=v.i;
  return (u16)((i + 0x7fffu + ((i>>16)&1u)) >> 16); }

// ---------- dtype detection ----------
__global__ __launch_bounds__(256) void k_detect(const u16* __restrict__ p, int n,
                                                u32* __restrict__ maxbits, int* __restrict__ zcnt){
  int i0 = blockIdx.x*256 + threadIdx.x;
  float lm = 0.f; int lz = 0;
  for (int i = i0; i < n; i += gridDim.x*256){
    u16 v = p[i];
    if (v == 0) lz++;
    float f = fabsf(b2f(v));
    lm = fmaxf(lm, f);
  }
  #pragma unroll
  for (int off = 32; off; off >>= 1){
    lm = fmaxf(lm, __shfl_down(lm, off));
    lz += __shfl_down(lz, off);
  }
  if ((threadIdx.x & 63) == 0){
    atomicMax(maxbits, __float_as_uint(lm));
    atomicAdd(zcnt, lz);
  }
}

__global__ void k_setflag(const u32* maxbits, const int* zcnt, int n, int* flag){
  float m = __uint_as_float(*maxbits);
  *flag = (m > 1e6f || *zcnt > n/4) ? 1 : 0;   // 1 => inputs are f32
}

__global__ __launch_bounds__(256) void k_conv(const void* __restrict__ src, float* __restrict__ dst,
                                              int n, const int* __restrict__ flag){
  int i = blockIdx.x*256 + threadIdx.x;
  if (i >= n) return;
  if (*flag) dst[i] = ((const float*)src)[i];
  else       dst[i] = b2f(((const u16*)src)[i]);
}

__global__ __launch_bounds__(256) void k_store(const float* __restrict__ x, const float* __restrict__ c,
                                               void* __restrict__ out, const int* __restrict__ flag){
  int i = blockIdx.x*256 + threadIdx.x;
  int tot = Nn*32 + NCc*32;
  if (i >= tot) return;
  float v = (i < Nn*32) ? x[i] : c[i - Nn*32];
  if (*flag) ((float*)out)[i] = v;
  else       ((u16*)out)[i]   = f2b(v);
}

__global__ __launch_bounds__(256) void k_count(const int* __restrict__ idx, int n, int* __restrict__ deg){
  int i = blockIdx.x*256 + threadIdx.x;
  if (i < n) atomicAdd(&deg[idx[i]], 1);
}

// ---------- weight pack: Wp[col][i] bf16, col in [0,1088), i in [0,32) ----------
__global__ __launch_bounds__(256) void k_wpack(const float* __restrict__ W2, const float* __restrict__ b2v,
                                               const float* __restrict__ rw, u16* __restrict__ Wp){
  int i = blockIdx.x*256 + threadIdx.x;   // i = col*32 + ii
  if (i >= TCOLS*32) return;
  int col = i >> 5, ii = i & 31;
  float v;
  if (col < 1024)      v = W2[((col>>5)<<10) + (ii<<5) + (col&31)];
  else if (col < 1056) v = b2v[(ii<<5) + (col-1024)];
  else                 v = rw[(ii<<5) + (col-1056)];
  Wp[i] = f2b(v);
}

// ---------- MFMA feat gemm: T[M x 1088] = X[M x 32] * B[32 x 1088], T bf16 ----------
// Swapped operands: D = Wp(M-dim=cols) * X^T(N-dim=nodes); lane's 4 acc regs are
// 4 CONSECUTIVE T columns of one node -> 8B dwordx2 store.
// wave = 16 nodes x 17 col-tiles; blockIdx.y in [0,4) picks the tile quarter.
__global__ __launch_bounds__(256) void k_feat_gemm_mfma(const float* __restrict__ x, int M,
                            const u16* __restrict__ Wp, const float* __restrict__ rb,
                            u16* __restrict__ T){
  int wave = threadIdx.x >> 6;
  int lane = threadIdx.x & 63;
  int quad = lane >> 4, lm = lane & 15;
  int ntile = blockIdx.x*64 + wave*16;
  int n = ntile + lm;
  int nc = n < M ? n : M-1;
  const float* xp = x + (size_t)nc*32 + quad*8;
  s16x8 bfrag;                       // B[k][node]: lane holds x[node=lm][k=quad*8+j]
  #pragma unroll
  for (int j = 0; j < 8; j++) bfrag[j] = (short)f2b(xp[j]);
  int t0 = blockIdx.y * 17;
  for (int ti = 0; ti < 17; ti++){
    int colbase = (t0 + ti) * 16;
    // A[m][k]: lane holds Wp[col=colbase+lm][k=quad*8+j]
    s16x8 afrag = *(const s16x8*)(Wp + (size_t)(colbase + lm)*32 + quad*8);
    f32x4 acc = {0.f, 0.f, 0.f, 0.f};
    acc = __builtin_amdgcn_mfma_f32_16x16x32_bf16(afrag, bfrag, acc, 0, 0, 0);
    if (n < M){
      int cb = colbase + quad*4;     // 4 consecutive cols for this lane
      float r0=0.f, r1=0.f, r2=0.f, r3=0.f;
      if (cb >= 1056){ r0=rb[cb-1056]; r1=rb[cb-1055]; r2=rb[cb-1054]; r3=rb[cb-1053]; }
      u32 lo = (u32)f2b(acc[0]+r0) | ((u32)f2b(acc[1]+r1) << 16);
      u32 hi = (u32)f2b(acc[2]+r2) | ((u32)f2b(acc[3]+r3) << 16);
      *(uint2*)(T + (size_t)n*TCOLS + cb) = make_uint2(lo, hi);
    }
  }
}

// ---------- fused edge MLP + message + scatter ----------
// phase 1: 16 edges/block, h = relu(ef@w1+b1) computed in-block into LDS
// phase 2: msg[e][o] = sum_{k<33} h'[e][k]*T[src[e]][k][o], atomic into agg[dst]
__global__ __launch_bounds__(256) void k_edge_msg(const int* __restrict__ src, const int* __restrict__ dst, int E_,
                           const float* __restrict__ ef,
                           const float* __restrict__ w1, const float* __restrict__ b1,
                           const u16* __restrict__ T, float* __restrict__ agg){
  __shared__ float w1s[256], b1s[32], efs[16][8];
  __shared__ float hs[16][34];
  int tid = threadIdx.x;
  int e0 = blockIdx.x * 16;
  int el = tid >> 4, kk = tid & 15;
  w1s[tid] = w1[tid];
  if (tid < 32) b1s[tid] = b1[tid];
  if (kk < 8){
    int e = e0 + el;
    efs[el][kk] = (e < E_) ? ef[(size_t)e*8 + kk] : 0.f;
  }
  __syncthreads();
  {
    float a0 = b1s[2*kk], a1 = b1s[2*kk+1];
    #pragma unroll
    for (int j = 0; j < 8; j++){
      float e = efs[el][j];
      a0 += e * w1s[j*32 + 2*kk];
      a1 += e * w1s[j*32 + 2*kk+1];
    }
    hs[el][2*kk]   = fmaxf(a0, 0.f);
    hs[el][2*kk+1] = fmaxf(a1, 0.f);
    if (kk == 0) hs[el][32] = 1.0f;
  }
  __syncthreads();
  int e = e0 + el;
  if (e >= E_) return;
  int sn = src[e], dn = dst[e];
  int op = kk;
  const u32* Tp = (const u32*)T + (size_t)sn*(TCOLS/2) + op;
  float a0 = 0.f, a1 = 0.f;
  #pragma unroll
  for (int k = 0; k < 33; k++){
    u32 v = Tp[(size_t)k*16];
    float hk = hs[el][k];
    a0 += hk * bfl(v);
    a1 += hk * bfh(v);
  }
  float* ap = agg + (size_t)dn*32 + 2*op;
  atomicAdd(ap,   a0);
  atomicAdd(ap+1, a1);
}

__global__ __launch_bounds__(256) void k_update_relu(const float* __restrict__ agg, const int* __restrict__ deg,
                              const u16* __restrict__ T, int M, float* __restrict__ out){
  int i = blockIdx.x*256 + threadIdx.x;
  if (i >= M*32) return;
  int n = i >> 5, o = i & 31;
  int dg = deg[n];
  float d = (float)(dg > 1 ? dg : 1);
  float v = agg[i]/d + b2f(T[(size_t)n*TCOLS + 1056 + o]);
  out[i] = fmaxf(v, 0.f);
}

__global__ __launch_bounds__(256) void k_lin32(const float* __restrict__ x, int M,
                        const float* __restrict__ w, const float* __restrict__ b,
                        float* __restrict__ out){
  __shared__ float wsm[1024], bs[32];
  int tid = threadIdx.x;
  for (int idx = tid; idx < 1024; idx += 256) wsm[idx] = w[idx];
  if (tid < 32) bs[tid] = b[tid];
  __syncthreads();
  int i = blockIdx.x*256 + tid;
  if (i >= M*32) return;
  int n = i >> 5, o = i & 31;
  const float* xr = x + (size_t)n*32;
  float acc = bs[o];
  #pragma unroll
  for (int j = 0; j < 32; j++) acc += xr[j]*wsm[j*32+o];
  out[i] = acc;
}

__global__ __launch_bounds__(256) void k_scatter(const int* __restrict__ gidx, const int* __restrict__ sidx, int A_,
                          const float* __restrict__ m, float* __restrict__ agg){
  int i = blockIdx.x*256 + threadIdx.x;
  if (i >= A_*32) return;
  int a = i >> 5, o = i & 31;
  atomicAdd(&agg[(size_t)sidx[a]*32 + o], m[(size_t)gidx[a]*32 + o]);
}

__global__ __launch_bounds__(256) void k_add_mean(const float* __restrict__ base, const float* __restrict__ agg,
                           const int* __restrict__ deg, int M, float* __restrict__ out){
  int i = blockIdx.x*256 + threadIdx.x;
  if (i >= M*32) return;
  int n = i >> 5;
  int dg = deg[n];
  float d = (float)(dg > 1 ? dg : 1);
  out[i] = base[i] + agg[i]/d;
}

extern "C" void kernel_launch(void* const* d_in, const int* in_sizes, int n_in,
                              void* d_out, int out_size, void* d_ws, size_t ws_size,
                              hipStream_t stream){
  const int* ei  = (const int*)d_in[1];
  const int* n2c = (const int*)d_in[4];
  const int* cei = (const int*)d_in[5];

  char* ws = (char*)d_ws;
  size_t off = 0;
  auto alloc = [&](size_t bytes){ void* p = ws + off; off += (bytes + 255) & ~(size_t)255; return p; };

  u32* maxbits = (u32*)alloc(256);
  int* zcnt = (int*)((char*)maxbits + 4);
  int* flag = (int*)((char*)maxbits + 8);

  float* xA   = (float*)alloc((size_t)Nn*32*4);
  float* xB   = (float*)alloc((size_t)Nn*32*4);
  float* cA   = (float*)alloc((size_t)NCc*32*4);
  float* cB   = (float*)alloc((size_t)NCc*32*4);
  float* m    = (float*)alloc((size_t)Nn*32*4);
  float* agg  = (float*)alloc((size_t)Nn*32*4);
  float* cagg = (float*)alloc((size_t)NCc*32*4);
  int* deg_nd  = (int*)alloc((size_t)Nn*4);
  int* deg_ce  = (int*)alloc((size_t)NCc*4);
  int* deg_n2c = (int*)alloc((size_t)NCc*4);
  int* deg_c2n = (int*)alloc((size_t)Nn*4);
  float* ef32  = (float*)alloc((size_t)Ee*8*4);
  float* cef32 = (float*)alloc((size_t)ECc*8*4);

  const int widx[16] = {7,8,9,10,11,12,13,14,15,16,17,18,19,20,21,22};
  float* wf[16];
  for (int j = 0; j < 16; j++) wf[j] = (float*)alloc((size_t)in_sizes[widx[j]]*4);

  u16* Wp  = (u16*)alloc((size_t)TCOLS*32*2);
  u16* Tb  = (u16*)alloc((size_t)Nn*TCOLS*2);

  auto nb = [](int n){ return (n + 255)/256; };

  // 1. dtype detection on node_features
  hipMemsetAsync(maxbits, 0, 256, stream);
  k_detect<<<256,256,0,stream>>>((const u16*)d_in[0], Nn*32, maxbits, zcnt);
  k_setflag<<<1,1,0,stream>>>(maxbits, zcnt, Nn*32, flag);

  // 2. convert all float tensors to f32
  k_conv<<<nb(Nn*32),256,0,stream>>>(d_in[0], xA, Nn*32, flag);
  k_conv<<<nb(NCc*32),256,0,stream>>>(d_in[3], cA, NCc*32, flag);
  k_conv<<<nb(Ee*8),256,0,stream>>>(d_in[2], ef32, Ee*8, flag);
  k_conv<<<nb(ECc*8),256,0,stream>>>(d_in[6], cef32, ECc*8, flag);
  for (int j = 0; j < 16; j++)
    k_conv<<<nb(in_sizes[widx[j]]),256,0,stream>>>(d_in[widx[j]], wf[j], in_sizes[widx[j]], flag);

  const float *nn1w=wf[0], *nn1b=wf[1], *nn2w=wf[2], *nn2b=wf[3], *rootw=wf[4], *rootb=wf[5],
              *n2cw=wf[6], *n2cb=wf[7], *cnn1w=wf[8], *cnn1b=wf[9], *cnn2w=wf[10], *cnn2b=wf[11],
              *crootw=wf[12], *crootb=wf[13], *c2nw=wf[14], *c2nb=wf[15];

  // 3. degrees
  hipMemsetAsync(deg_nd, 0, (size_t)Nn*4, stream);
  hipMemsetAsync(deg_ce, 0, (size_t)NCc*4, stream);
  hipMemsetAsync(deg_n2c, 0, (size_t)NCc*4, stream);
  hipMemsetAsync(deg_c2n, 0, (size_t)Nn*4, stream);
  k_count<<<nb(Ee),256,0,stream>>>(ei + Ee, Ee, deg_nd);
  k_count<<<nb(ECc),256,0,stream>>>(cei + ECc, ECc, deg_ce);
  k_count<<<nb(Aa),256,0,stream>>>(n2c + Aa, Aa, deg_n2c);
  k_count<<<nb(Aa),256,0,stream>>>(n2c, Aa, deg_c2n);

  // 4. pipeline
  for (int l = 0; l < 2; l++){
    // ---- node NNConv ----
    k_wpack<<<nb(TCOLS*32),256,0,stream>>>(nn2w + (size_t)l*32768, nn2b + l*1024, rootw + l*1024, Wp);
    k_feat_gemm_mfma<<<dim3((Nn+63)/64,4),256,0,stream>>>(xA, Nn, Wp, rootb + l*32, Tb);
    hipMemsetAsync(agg, 0, (size_t)Nn*32*4, stream);
    k_edge_msg<<<(Ee+15)/16,256,0,stream>>>(ei, ei+Ee, Ee, ef32, nn1w + l*256, nn1b + l*32, Tb, agg);
    k_update_relu<<<nb(Nn*32),256,0,stream>>>(agg, deg_nd, Tb, Nn, xB);
    // ---- Node2Clique ----
    k_lin32<<<nb(Nn*32),256,0,stream>>>(xB, Nn, n2cw + l*1024, n2cb + l*32, m);
    hipMemsetAsync(cagg, 0, (size_t)NCc*32*4, stream);
    k_scatter<<<nb(Aa*32),256,0,stream>>>(n2c, n2c+Aa, Aa, m, cagg);
    k_add_mean<<<nb(NCc*32),256,0,stream>>>(cA, cagg, deg_n2c, NCc, cB);
    // ---- clique NNConv ----
    k_wpack<<<nb(TCOLS*32),256,0,stream>>>(cnn2w + (size_t)l*32768, cnn2b + l*1024, crootw + l*1024, Wp);
    k_feat_gemm_mfma<<<dim3((NCc+63)/64,4),256,0,stream>>>(cB, NCc, Wp, crootb + l*32, Tb);
    hipMemsetAsync(cagg, 0, (size_t)NCc*32*4, stream);
    k_edge_msg<<<(ECc+15)/16,256,0,stream>>>(cei, cei+ECc, ECc, cef32, cnn1w + l*256, cnn1b + l*32, Tb, cagg);
    k_update_relu<<<nb(NCc*32),256,0,stream>>>(cagg, deg_ce, Tb, NCc, cA);
    // ---- Clique2Node ----
    k_lin32<<<nb(NCc*32),256,0,stream>>>(cA, NCc, c2nw + l*1024, c2nb + l*32, m);
    hipMemsetAsync(agg, 0, (size_t)Nn*32*4, stream);
    k_scatter<<<nb(Aa*32),256,0,stream>>>(n2c+Aa, n2c, Aa, m, agg);
    k_add_mean<<<nb(Nn*32),256,0,stream>>>(xB, agg, deg_c2n, Nn, xA);
  }
  k_store<<<nb(Nn*32 + NCc*32),256,0,stream>>>(xA, cA, d_out, flag);
}

// Round 5
// 393.638 us; speedup vs baseline: 2.0686x; 1.1641x over previous
//
#include <hip/hip_runtime.h>
#include <hip/hip_bf16.h>

typedef unsigned int u32;
typedef unsigned short u16;

#define DEVINL __device__ __forceinline__

constexpr int Nn  = 25000;
constexpr int Ee  = 100000;
constexpr int NCc = 8000;
constexpr int Aa  = 50000;
constexpr int ECc = 24000;
constexpr int TCOLS = 1088;   // 34 rows * 32 cols: k=0..31 -> T, k=32 -> x@b2, k=33 -> x@rootw+rootb
constexpr int NB_N = (Nn + 255)/256;   // 98 scan blocks (node)
constexpr int NB_C = (NCc + 255)/256;  // 32 scan blocks (clique)

typedef float f32x4 __attribute__((ext_vector_type(4)));
typedef short s16x8 __attribute__((ext_vector_type(8)));

DEVINL float b2f(u16 u){ union{u32 i;float f;}v; v.i = ((u32)u)<<16; return v.f; }
DEVINL float bfl(u32 u){ union{u32 i;float f;}v; v.i = u<<16; return v.f; }
DEVINL float bfh(u32 u){ union{u32 i;float f;}v; v.i = u & 0xffff0000u; return v.f; }
DEVINL u16 f2b(float f){ union{float f;u32 i;}v; v.f=f; u32 i=v.i;
  return (u16)((i + 0x7fffu + ((i>>16)&1u)) >> 16); }
// flag-aware raw weight read: flag=1 -> f32, flag=0 -> bf16
DEVINL float ldw(const void* p, long i, int f){
  return f ? ((const float*)p)[i] : b2f(((const u16*)p)[i]);
}

// ---------- dtype detection ----------
__global__ __launch_bounds__(256) void k_detect(const u16* __restrict__ p, int n,
                                                u32* __restrict__ maxbits, int* __restrict__ zcnt){
  int i0 = blockIdx.x*256 + threadIdx.x;
  float lm = 0.f; int lz = 0;
  for (int i = i0; i < n; i += gridDim.x*256){
    u16 v = p[i];
    if (v == 0) lz++;
    lm = fmaxf(lm, fabsf(b2f(v)));
  }
  #pragma unroll
  for (int off = 32; off; off >>= 1){
    lm = fmaxf(lm, __shfl_down(lm, off));
    lz += __shfl_down(lz, off);
  }
  if ((threadIdx.x & 63) == 0){
    atomicMax(maxbits, __float_as_uint(lm));
    atomicAdd(zcnt, lz);
  }
}

__global__ void k_setflag(const u32* maxbits, const int* zcnt, int n, int* flag){
  float m = __uint_as_float(*maxbits);
  *flag = (m > 1e6f || *zcnt > n/4) ? 1 : 0;   // 1 => inputs are f32
}

__global__ __launch_bounds__(256) void k_conv(const void* __restrict__ src, float* __restrict__ dst,
                                              int n, const int* __restrict__ flag){
  int i = blockIdx.x*256 + threadIdx.x;
  if (i >= n) return;
  dst[i] = ldw(src, i, *flag);
}

__global__ __launch_bounds__(256) void k_store(const float* __restrict__ x, const float* __restrict__ c,
                                               void* __restrict__ out, const int* __restrict__ flag){
  int i = blockIdx.x*256 + threadIdx.x;
  int tot = Nn*32 + NCc*32;
  if (i >= tot) return;
  float v = (i < Nn*32) ? x[i] : c[i - Nn*32];
  if (*flag) ((float*)out)[i] = v;
  else       ((u16*)out)[i]   = f2b(v);
}

// ---------- all degree/count histograms in one kernel ----------
__global__ __launch_bounds__(256) void k_count_all(const int* __restrict__ ei, const int* __restrict__ cei,
                          const int* __restrict__ n2c,
                          int* __restrict__ deg_nd, int* __restrict__ deg_ce,
                          int* __restrict__ deg_n2c, int* __restrict__ deg_c2n,
                          int* __restrict__ cnt_sn, int* __restrict__ cnt_sc){
  int i = blockIdx.x*256 + threadIdx.x;
  if (i < Ee)                             atomicAdd(&deg_nd[ei[Ee + i]], 1);
  else if ((i -= Ee) < ECc)               atomicAdd(&deg_ce[cei[ECc + i]], 1);
  else if ((i -= ECc) < Aa)               atomicAdd(&deg_n2c[n2c[Aa + i]], 1);
  else if ((i -= Aa) < Aa)                atomicAdd(&deg_c2n[n2c[i]], 1);
  else if ((i -= Aa) < Ee)                atomicAdd(&cnt_sn[ei[i]], 1);
  else if ((i -= Ee) < ECc)               atomicAdd(&cnt_sc[cei[i]], 1);
}

// ---------- counting-sort of edges by src: block scan / spine / fix / place ----------
__global__ __launch_bounds__(256) void k_scan_block(const int* __restrict__ cnt_n, const int* __restrict__ cnt_c,
                           int* __restrict__ offs_n, int* __restrict__ offs_c,
                           int* __restrict__ bsum_n, int* __restrict__ bsum_c){
  __shared__ int s[256];
  bool isC = blockIdx.x >= NB_N;
  int bid = isC ? blockIdx.x - NB_N : blockIdx.x;
  const int* cnt = isC ? cnt_c : cnt_n;
  int M = isC ? NCc : Nn;
  int tid = threadIdx.x;
  int i = bid*256 + tid;
  int v = (i < M) ? cnt[i] : 0;
  s[tid] = v; __syncthreads();
  for (int d = 1; d < 256; d <<= 1){
    int t = (tid >= d) ? s[tid-d] : 0;
    __syncthreads();
    s[tid] += t;
    __syncthreads();
  }
  if (i < M) (isC ? offs_c : offs_n)[i] = s[tid] - v;
  if (tid == 255) (isC ? bsum_c : bsum_n)[bid] = s[255];
}

__global__ __launch_bounds__(256) void k_spine(int* __restrict__ bn, int* __restrict__ bc){
  __shared__ int s[256];
  int tid = threadIdx.x;
  int v;
  if (tid < 128) v = (tid < NB_N) ? bn[tid] : 0;
  else           v = (tid-128 < NB_C) ? bc[tid-128] : 0;
  s[tid] = v; __syncthreads();
  for (int d = 1; d < 128; d <<= 1){
    int lane = tid & 127;
    int t = (lane >= d) ? s[tid-d] : 0;
    __syncthreads();
    s[tid] += t;
    __syncthreads();
  }
  if (tid < NB_N) bn[tid] = s[tid] - v;
  else if (tid >= 128 && tid-128 < NB_C) bc[tid-128] = s[tid] - v;
}

__global__ __launch_bounds__(256) void k_scan_fix(int* __restrict__ offs_n, int* __restrict__ offs_c,
                         const int* __restrict__ bn, const int* __restrict__ bc){
  int i = blockIdx.x*256 + threadIdx.x;
  if (i < Nn) offs_n[i] += bn[i >> 8];
  else if ((i -= Nn) < NCc) offs_c[i] += bc[i >> 8];
}

__global__ __launch_bounds__(256) void k_place(const int* __restrict__ ei, const int* __restrict__ cei,
                      const int* __restrict__ offs_n, const int* __restrict__ offs_c,
                      int* __restrict__ cur_n, int* __restrict__ cur_c,
                      int* __restrict__ perm_n, int* __restrict__ perm_c){
  int i = blockIdx.x*256 + threadIdx.x;
  if (i < Ee){
    int s = ei[i];
    perm_n[offs_n[s] + atomicAdd(&cur_n[s], 1)] = i;
  } else if ((i -= Ee) < ECc){
    int s = cei[i];
    perm_c[offs_c[s] + atomicAdd(&cur_c[s], 1)] = i;
  }
}

// ---------- weight pack: Wp[col][i] bf16 ----------
__global__ __launch_bounds__(256) void k_wpack(const void* __restrict__ W2, long w2off,
                      const void* __restrict__ b2v, long b2off,
                      const void* __restrict__ rw, long rwoff,
                      const int* __restrict__ flag, u16* __restrict__ Wp){
  int i = blockIdx.x*256 + threadIdx.x;
  if (i >= TCOLS*32) return;
  int col = i >> 5, ii = i & 31;
  int f = *flag;
  float v;
  if (col < 1024)      v = ldw(W2, w2off + ((col>>5)<<10) + (ii<<5) + (col&31), f);
  else if (col < 1056) v = ldw(b2v, b2off + (ii<<5) + (col-1024), f);
  else                 v = ldw(rw, rwoff + (ii<<5) + (col-1056), f);
  Wp[i] = f2b(v);
}

// ---------- MFMA feat gemm (swapped operands; 4 consecutive cols/lane -> 8B store) ----------
__global__ __launch_bounds__(256) void k_feat_gemm_mfma(const float* __restrict__ x, int M,
                            const u16* __restrict__ Wp,
                            const void* __restrict__ rb, long rboff, const int* __restrict__ flag,
                            u16* __restrict__ T){
  int wave = threadIdx.x >> 6;
  int lane = threadIdx.x & 63;
  int quad = lane >> 4, lm = lane & 15;
  int ntile = blockIdx.x*64 + wave*16;
  int n = ntile + lm;
  int nc = n < M ? n : M-1;
  int f = *flag;
  const float* xp = x + (size_t)nc*32 + quad*8;
  s16x8 bfrag;
  #pragma unroll
  for (int j = 0; j < 8; j++) bfrag[j] = (short)f2b(xp[j]);
  int t0 = blockIdx.y * 17;
  for (int ti = 0; ti < 17; ti++){
    int colbase = (t0 + ti) * 16;
    s16x8 afrag = *(const s16x8*)(Wp + (size_t)(colbase + lm)*32 + quad*8);
    f32x4 acc = {0.f, 0.f, 0.f, 0.f};
    acc = __builtin_amdgcn_mfma_f32_16x16x32_bf16(afrag, bfrag, acc, 0, 0, 0);
    if (n < M){
      int cb = colbase + quad*4;
      float r0=0.f, r1=0.f, r2=0.f, r3=0.f;
      if (cb >= 1056){
        r0 = ldw(rb, rboff+cb-1056, f); r1 = ldw(rb, rboff+cb-1055, f);
        r2 = ldw(rb, rboff+cb-1054, f); r3 = ldw(rb, rboff+cb-1053, f);
      }
      u32 lo = (u32)f2b(acc[0]+r0) | ((u32)f2b(acc[1]+r1) << 16);
      u32 hi = (u32)f2b(acc[2]+r2) | ((u32)f2b(acc[3]+r3) << 16);
      *(uint2*)(T + (size_t)n*TCOLS + cb) = make_uint2(lo, hi);
    }
  }
}

// ---------- fused edge MLP + message + scatter, src-sorted via perm ----------
__global__ __launch_bounds__(256) void k_edge_msg(const int* __restrict__ src, const int* __restrict__ dst,
                           const int* __restrict__ perm, int E_,
                           const void* __restrict__ ef,
                           const void* __restrict__ w1, long w1off,
                           const void* __restrict__ b1, long b1off,
                           const int* __restrict__ flag,
                           const u16* __restrict__ T, float* __restrict__ agg){
  __shared__ float w1s[256], b1s[32], efs[16][8];
  __shared__ float hs[16][34];
  __shared__ int pe[16];
  int tid = threadIdx.x;
  // XCD-chunked block remap: contiguous sorted-edge (and thus T-row) range per XCD
  int B = (E_ + 15)/16;
  int chunk = gridDim.x >> 3;
  int nb = (blockIdx.x & 7)*chunk + (blockIdx.x >> 3);
  if (nb >= B) return;
  int f = *flag;
  w1s[tid] = ldw(w1, w1off + tid, f);
  if (tid < 32) b1s[tid] = ldw(b1, b1off + tid, f);
  int e0 = nb * 16;
  if (tid < 16) pe[tid] = (e0 + tid < E_) ? perm[e0 + tid] : -1;
  __syncthreads();
  int el = tid >> 4, kk = tid & 15;
  int e = pe[el];
  if (kk < 8) efs[el][kk] = (e >= 0) ? ldw(ef, (long)e*8 + kk, f) : 0.f;
  __syncthreads();
  {
    float a0 = b1s[2*kk], a1 = b1s[2*kk+1];
    #pragma unroll
    for (int j = 0; j < 8; j++){
      float ev = efs[el][j];
      a0 += ev * w1s[j*32 + 2*kk];
      a1 += ev * w1s[j*32 + 2*kk+1];
    }
    hs[el][2*kk]   = fmaxf(a0, 0.f);
    hs[el][2*kk+1] = fmaxf(a1, 0.f);
    if (kk == 0) hs[el][32] = 1.0f;
  }
  __syncthreads();
  if (e < 0) return;
  int sn = src[e], dn = dst[e];
  const u32* Tp = (const u32*)T + (size_t)sn*(TCOLS/2) + kk;
  float a0 = 0.f, a1 = 0.f;
  #pragma unroll
  for (int k = 0; k < 33; k++){
    u32 v = Tp[(size_t)k*16];
    float hk = hs[el][k];
    a0 += hk * bfl(v);
    a1 += hk * bfh(v);
  }
  float* ap = agg + (size_t)dn*32 + 2*kk;
  atomicAdd(ap,   a0);
  atomicAdd(ap+1, a1);
}

// ---------- fused: feat = relu(agg/deg + Troot); m = feat @ w + b ----------
__global__ __launch_bounds__(256) void k_update_lin(const float* __restrict__ agg, const int* __restrict__ deg,
                           const u16* __restrict__ T, int M,
                           const void* __restrict__ w, long woff,
                           const void* __restrict__ b, long boff,
                           const int* __restrict__ flag,
                           float* __restrict__ feat, float* __restrict__ m_out){
  __shared__ float wsm[1024], bs[32], rows[8][33];
  int tid = threadIdx.x;
  int f = *flag;
  for (int idx = tid; idx < 1024; idx += 256) wsm[idx] = ldw(w, woff + idx, f);
  if (tid < 32) bs[tid] = ldw(b, boff + tid, f);
  int nl = tid >> 5, o = tid & 31;
  int n = blockIdx.x*8 + nl;
  if (n < M){
    int dg = deg[n];
    float d = (float)(dg > 1 ? dg : 1);
    float v = fmaxf(agg[(size_t)n*32 + o]/d + b2f(T[(size_t)n*TCOLS + 1056 + o]), 0.f);
    rows[nl][o] = v;
    feat[(size_t)n*32 + o] = v;
  }
  __syncthreads();
  if (n >= M) return;
  float acc = bs[o];
  #pragma unroll
  for (int j = 0; j < 32; j++) acc += rows[nl][j]*wsm[j*32+o];
  m_out[(size_t)n*32 + o] = acc;
}

__global__ __launch_bounds__(256) void k_scatter(const int* __restrict__ gidx, const int* __restrict__ sidx, int A_,
                          const float* __restrict__ m, float* __restrict__ agg){
  int i = blockIdx.x*256 + threadIdx.x;
  if (i >= A_*32) return;
  int a = i >> 5, o = i & 31;
  atomicAdd(&agg[(size_t)sidx[a]*32 + o], m[(size_t)gidx[a]*32 + o]);
}

__global__ __launch_bounds__(256) void k_add_mean(const float* __restrict__ base, const float* __restrict__ agg,
                           const int* __restrict__ deg, int M, float* __restrict__ out){
  int i = blockIdx.x*256 + threadIdx.x;
  if (i >= M*32) return;
  int n = i >> 5;
  int dg = deg[n];
  float d = (float)(dg > 1 ? dg : 1);
  out[i] = base[i] + agg[i]/d;
}

extern "C" void kernel_launch(void* const* d_in, const int* in_sizes, int n_in,
                              void* d_out, int out_size, void* d_ws, size_t ws_size,
                              hipStream_t stream){
  const int* ei  = (const int*)d_in[1];
  const int* n2c = (const int*)d_in[4];
  const int* cei = (const int*)d_in[5];
  const void *efr = d_in[2], *cefr = d_in[6];
  const void *nn1w = d_in[7], *nn1b = d_in[8], *nn2w = d_in[9], *nn2b = d_in[10],
             *rootw = d_in[11], *rootb = d_in[12], *n2cw = d_in[13], *n2cb = d_in[14],
             *cnn1w = d_in[15], *cnn1b = d_in[16], *cnn2w = d_in[17], *cnn2b = d_in[18],
             *crootw = d_in[19], *crootb = d_in[20], *c2nw = d_in[21], *c2nb = d_in[22];

  char* ws = (char*)d_ws;
  size_t off = 0;
  auto alloc = [&](size_t bytes){ void* p = ws + off; off += (bytes + 255) & ~(size_t)255; return p; };

  // ---- zeroed region (single memset) ----
  size_t zstart = off;
  float *aggE[2], *caggS[2], *caggE[2], *aggS[2];
  for (int l = 0; l < 2; l++){
    aggE[l]  = (float*)alloc((size_t)Nn*32*4);
    caggS[l] = (float*)alloc((size_t)NCc*32*4);
    caggE[l] = (float*)alloc((size_t)NCc*32*4);
    aggS[l]  = (float*)alloc((size_t)Nn*32*4);
  }
  int* deg_nd  = (int*)alloc((size_t)Nn*4);
  int* deg_ce  = (int*)alloc((size_t)NCc*4);
  int* deg_n2c = (int*)alloc((size_t)NCc*4);
  int* deg_c2n = (int*)alloc((size_t)Nn*4);
  int* cnt_sn  = (int*)alloc((size_t)Nn*4);
  int* cnt_sc  = (int*)alloc((size_t)NCc*4);
  int* cur_n   = (int*)alloc((size_t)Nn*4);
  int* cur_c   = (int*)alloc((size_t)NCc*4);
  u32* maxbits = (u32*)alloc(256);
  int* zcnt = (int*)((char*)maxbits + 4);
  int* flag = (int*)((char*)maxbits + 8);
  size_t zbytes = off - zstart;

  // ---- non-zeroed ----
  float* xA = (float*)alloc((size_t)Nn*32*4);
  float* xB = (float*)alloc((size_t)Nn*32*4);
  float* cA = (float*)alloc((size_t)NCc*32*4);
  float* cB = (float*)alloc((size_t)NCc*32*4);
  float* m  = (float*)alloc((size_t)Nn*32*4);
  int* offs_n = (int*)alloc((size_t)Nn*4);
  int* offs_c = (int*)alloc((size_t)NCc*4);
  int* bsum_n = (int*)alloc(512);
  int* bsum_c = (int*)alloc(512);
  int* perm_n = (int*)alloc((size_t)Ee*4);
  int* perm_c = (int*)alloc((size_t)ECc*4);
  u16* Wp = (u16*)alloc((size_t)TCOLS*32*2);
  u16* Tb = (u16*)alloc((size_t)Nn*TCOLS*2);

  auto nb = [](int n){ return (n + 255)/256; };

  // 1. single memset of all accumulators/counters/scratch
  hipMemsetAsync(ws + zstart, 0, zbytes, stream);

  // 2. dtype detection
  k_detect<<<256,256,0,stream>>>((const u16*)d_in[0], Nn*32, maxbits, zcnt);
  k_setflag<<<1,1,0,stream>>>(maxbits, zcnt, Nn*32, flag);

  // 3. feature conversion (weights are read raw+flag in consumers)
  k_conv<<<nb(Nn*32),256,0,stream>>>(d_in[0], xA, Nn*32, flag);
  k_conv<<<nb(NCc*32),256,0,stream>>>(d_in[3], cA, NCc*32, flag);

  // 4. histograms + counting-sort of both edge lists by src
  k_count_all<<<nb(Ee+ECc+Aa+Aa+Ee+ECc),256,0,stream>>>(ei, cei, n2c,
      deg_nd, deg_ce, deg_n2c, deg_c2n, cnt_sn, cnt_sc);
  k_scan_block<<<NB_N+NB_C,256,0,stream>>>(cnt_sn, cnt_sc, offs_n, offs_c, bsum_n, bsum_c);
  k_spine<<<1,256,0,stream>>>(bsum_n, bsum_c);
  k_scan_fix<<<nb(Nn+NCc),256,0,stream>>>(offs_n, offs_c, bsum_n, bsum_c);
  k_place<<<nb(Ee+ECc),256,0,stream>>>(ei, cei, offs_n, offs_c, cur_n, cur_c, perm_n, perm_c);

  int Bn = ((Ee+15)/16 + 7)/8*8;    // edge_msg grids, multiple of 8 for XCD chunking
  int Bc = ((ECc+15)/16 + 7)/8*8;

  // 5. the 2-layer pipeline
  for (int l = 0; l < 2; l++){
    // ---- node NNConv ----
    k_wpack<<<nb(TCOLS*32),256,0,stream>>>(nn2w, (long)l*32768, nn2b, (long)l*1024,
                                           rootw, (long)l*1024, flag, Wp);
    k_feat_gemm_mfma<<<dim3((Nn+63)/64,4),256,0,stream>>>(xA, Nn, Wp, rootb, (long)l*32, flag, Tb);
    k_edge_msg<<<Bn,256,0,stream>>>(ei, ei+Ee, perm_n, Ee, efr, nn1w, (long)l*256, nn1b, (long)l*32,
                                    flag, Tb, aggE[l]);
    k_update_lin<<<(Nn+7)/8,256,0,stream>>>(aggE[l], deg_nd, Tb, Nn, n2cw, (long)l*1024,
                                            n2cb, (long)l*32, flag, xB, m);
    // ---- Node2Clique ----
    k_scatter<<<nb(Aa*32),256,0,stream>>>(n2c, n2c+Aa, Aa, m, caggS[l]);
    k_add_mean<<<nb(NCc*32),256,0,stream>>>(cA, caggS[l], deg_n2c, NCc, cB);
    // ---- clique NNConv ----
    k_wpack<<<nb(TCOLS*32),256,0,stream>>>(cnn2w, (long)l*32768, cnn2b, (long)l*1024,
                                           crootw, (long)l*1024, flag, Wp);
    k_feat_gemm_mfma<<<dim3((NCc+63)/64,4),256,0,stream>>>(cB, NCc, Wp, crootb, (long)l*32, flag, Tb);
    k_edge_msg<<<Bc,256,0,stream>>>(cei, cei+ECc, perm_c, ECc, cefr, cnn1w, (long)l*256, cnn1b, (long)l*32,
                                    flag, Tb, caggE[l]);
    k_update_lin<<<(NCc+7)/8,256,0,stream>>>(caggE[l], deg_ce, Tb, NCc, c2nw, (long)l*1024,
                                             c2nb, (long)l*32, flag, cA, m);
    // ---- Clique2Node ----
    k_scatter<<<nb(Aa*32),256,0,stream>>>(n2c+Aa, n2c, Aa, m, aggS[l]);
    k_add_mean<<<nb(Nn*32),256,0,stream>>>(xB, aggS[l], deg_c2n, Nn, xA);
  }
  k_store<<<nb(Nn*32 + NCc*32),256,0,stream>>>(xA, cA, d_out, flag);
}